// Round 2
// baseline (162.338 us; speedup 1.0000x reference)
//
#include <hip/hip_runtime.h>
#include <math.h>

namespace {
constexpr int NV = 3;    // views
constexpr int NC = 16;   // channels
constexpr int ND = 32;   // depths
constexpr int NH = 256;
constexpr int NW = 320;
constexpr int HW = NH * NW;       // 81920
constexpr int DHW = ND * HW;      // 2621440
constexpr size_t FT_OFF = 128;    // ws bytes 0..95 = proj mats, 128.. = transposed feats
constexpr size_t FT_BYTES = (size_t)2 * HW * NC * sizeof(float);  // 10.5 MB
}

// ---------------------------------------------------------------------------
// Setup: proj_v = P_v @ inv(P_0); store rot(9)+trans(3) per src view.
// ---------------------------------------------------------------------------
__global__ void proj_setup_kernel(const float* __restrict__ pm,
                                  float* __restrict__ mats) {
    if (threadIdx.x != 0 || blockIdx.x != 0) return;
    float P[NV][4][4];
    for (int v = 0; v < NV; ++v) {
        const float* E = pm + v * 2 * 16;
        const float* K = pm + v * 2 * 16 + 16;
        for (int i = 0; i < 4; ++i)
            for (int j = 0; j < 4; ++j)
                P[v][i][j] = E[i * 4 + j];
        for (int i = 0; i < 3; ++i)
            for (int j = 0; j < 4; ++j) {
                float acc = 0.f;
                for (int k = 0; k < 3; ++k) acc += K[i * 4 + k] * E[k * 4 + j];
                P[v][i][j] = acc;
            }
    }
    float A[4][8];
    for (int i = 0; i < 4; ++i)
        for (int j = 0; j < 4; ++j) {
            A[i][j] = P[0][i][j];
            A[i][j + 4] = (i == j) ? 1.f : 0.f;
        }
    for (int col = 0; col < 4; ++col) {
        int piv = col;
        float best = fabsf(A[col][col]);
        for (int r = col + 1; r < 4; ++r) {
            float av = fabsf(A[r][col]);
            if (av > best) { best = av; piv = r; }
        }
        if (piv != col)
            for (int j = 0; j < 8; ++j) {
                float t = A[col][j]; A[col][j] = A[piv][j]; A[piv][j] = t;
            }
        float inv = 1.f / A[col][col];
        for (int j = 0; j < 8; ++j) A[col][j] *= inv;
        for (int r = 0; r < 4; ++r) {
            if (r == col) continue;
            float f = A[r][col];
            if (f != 0.f)
                for (int j = 0; j < 8; ++j) A[r][j] -= f * A[col][j];
        }
    }
    float Inv[4][4];
    for (int i = 0; i < 4; ++i)
        for (int j = 0; j < 4; ++j) Inv[i][j] = A[i][j + 4];

    for (int v = 1; v < NV; ++v) {
        float M[4][4];
        for (int i = 0; i < 4; ++i)
            for (int j = 0; j < 4; ++j) {
                float acc = 0.f;
                for (int k = 0; k < 4; ++k) acc += P[v][i][k] * Inv[k][j];
                M[i][j] = acc;
            }
        float* o = mats + (v - 1) * 12;
        for (int i = 0; i < 3; ++i)
            for (int j = 0; j < 3; ++j) o[i * 3 + j] = M[i][j];
        for (int i = 0; i < 3; ++i) o[9 + i] = M[i][3];
    }
}

// ---------------------------------------------------------------------------
// Transpose src views [C][HW] -> [HW][C] so a bilinear corner is 4x float4.
// Thread t: c4 = t&3, n = (t>>2)%HW, v = t/(HW*4). Writes are fully
// contiguous float4; reads are 16-consecutive-dword segments per c4 group.
// ---------------------------------------------------------------------------
__global__ __launch_bounds__(256) void transpose_kernel(
    const float* __restrict__ feats,  // [V][C][HW]
    float* __restrict__ ft)           // [2][HW][C]
{
    int tid = blockIdx.x * blockDim.x + threadIdx.x;  // 2*HW*4 exact
    int v = tid / (HW * 4);
    int r = tid - v * (HW * 4);
    int n = r >> 2;
    int c4 = r & 3;
    const float* src = feats + (size_t)(v + 1) * NC * HW + (size_t)c4 * 4 * HW + n;
    float4 o;
    o.x = src[0];
    o.y = src[HW];
    o.z = src[2 * HW];
    o.w = src[3 * HW];
    reinterpret_cast<float4*>(ft)[(size_t)v * HW * 4 + (size_t)n * 4 + c4] = o;
}

// ---------------------------------------------------------------------------
// Cost volume, vectorized gathers: one thread per (d,h,w); each corner is
// 4x dwordx4 from the transposed layout. Cost written into prob region.
// ---------------------------------------------------------------------------
__global__ __launch_bounds__(256) void cost_kernel2(
    const float* __restrict__ feats,   // [V][C][HW] (ref view reads)
    const float4* __restrict__ ft,     // [2][HW][4] float4
    const float* __restrict__ dvals,   // [D][HW]
    const float* __restrict__ wreg,    // [C]
    const float* __restrict__ mats,    // [2][12]
    float* __restrict__ cost)          // [D][HW]
{
    __shared__ float s_mat[24];
    __shared__ float s_w[NC];
    int t = threadIdx.x;
    if (t < 24) s_mat[t] = mats[t];
    if (t < NC) s_w[t] = wreg[t];
    __syncthreads();

    int tid = blockIdx.x * blockDim.x + t;
    int d = tid / HW;
    int n = tid - d * HW;
    int y = n / NW;
    int x = n - y * NW;
    float fx = (float)x, fy = (float)y;
    float depth = dvals[tid];

    float sum[NC], sq[NC];
#pragma unroll
    for (int c = 0; c < NC; ++c) {
        float r = feats[c * HW + n];   // ref view, coalesced
        sum[c] = r;
        sq[c] = r * r;
    }

#pragma unroll
    for (int v = 0; v < 2; ++v) {
        const float* m = s_mat + v * 12;
        float rx = m[0] * fx + m[1] * fy + m[2];
        float ry = m[3] * fx + m[4] * fy + m[5];
        float rz = m[6] * fx + m[7] * fy + m[8];
        float pxn = rx * depth + m[9];
        float pyn = ry * depth + m[10];
        float z   = rz * depth + m[11];
        z = (fabsf(z) < 1e-6f) ? 1e-6f : z;
        float rzi = __builtin_amdgcn_rcpf(z);   // ~1ulp approx; threshold 13.76
        float px = pxn * rzi, py = pyn * rzi;
        float x0f = floorf(px), y0f = floorf(py);
        float wx = px - x0f, wy = py - y0f;
        int x0 = (int)x0f, y0 = (int)y0f;
        int x1 = x0 + 1, y1 = y0 + 1;
        bool vx0 = (x0 >= 0) && (x0 < NW), vx1 = (x1 >= 0) && (x1 < NW);
        bool vy0 = (y0 >= 0) && (y0 < NH), vy1 = (y1 >= 0) && (y1 < NH);
        int cx0 = min(max(x0, 0), NW - 1), cx1 = min(max(x1, 0), NW - 1);
        int cy0 = min(max(y0, 0), NH - 1), cy1 = min(max(y1, 0), NH - 1);
        int i00 = cy0 * NW + cx0, i01 = cy0 * NW + cx1;
        int i10 = cy1 * NW + cx0, i11 = cy1 * NW + cx1;
        float w00 = (1.f - wx) * (1.f - wy) * ((vx0 && vy0) ? 1.f : 0.f);
        float w01 = wx * (1.f - wy) * ((vx1 && vy0) ? 1.f : 0.f);
        float w10 = (1.f - wx) * wy * ((vx0 && vy1) ? 1.f : 0.f);
        float w11 = wx * wy * ((vx1 && vy1) ? 1.f : 0.f);

        const float4* base = ft + (size_t)v * HW * 4;
        float4 g00[4], g01[4], g10[4], g11[4];
#pragma unroll
        for (int q = 0; q < 4; ++q) {
            g00[q] = base[(size_t)i00 * 4 + q];
            g01[q] = base[(size_t)i01 * 4 + q];
            g10[q] = base[(size_t)i10 * 4 + q];
            g11[q] = base[(size_t)i11 * 4 + q];
        }
#pragma unroll
        for (int q = 0; q < 4; ++q) {
            float v0 = g00[q].x * w00 + g01[q].x * w01 + g10[q].x * w10 + g11[q].x * w11;
            float v1 = g00[q].y * w00 + g01[q].y * w01 + g10[q].y * w10 + g11[q].y * w11;
            float v2 = g00[q].z * w00 + g01[q].z * w01 + g10[q].z * w10 + g11[q].z * w11;
            float v3 = g00[q].w * w00 + g01[q].w * w01 + g10[q].w * w10 + g11[q].w * w11;
            sum[4 * q + 0] += v0; sq[4 * q + 0] += v0 * v0;
            sum[4 * q + 1] += v1; sq[4 * q + 1] += v1 * v1;
            sum[4 * q + 2] += v2; sq[4 * q + 2] += v2 * v2;
            sum[4 * q + 3] += v3; sq[4 * q + 3] += v3 * v3;
        }
    }

    float cst = 0.f;
    const float invV = 1.f / 3.f;
#pragma unroll
    for (int c = 0; c < NC; ++c) {
        float s = sum[c] * invV;
        float var = sq[c] * invV - s * s;
        cst += var * s_w[c];
    }
    cost[tid] = cst;
}

// ---------------------------------------------------------------------------
// Fallback (R1 kernel) if ws_size can't hold the transposed features.
// ---------------------------------------------------------------------------
__global__ __launch_bounds__(256) void cost_kernel(
    const float* __restrict__ feats, const float* __restrict__ dvals,
    const float* __restrict__ wreg, const float* __restrict__ mats,
    float* __restrict__ cost)
{
    __shared__ float s_mat[24];
    __shared__ float s_w[NC];
    int t = threadIdx.x;
    if (t < 24) s_mat[t] = mats[t];
    if (t < NC) s_w[t] = wreg[t];
    __syncthreads();
    int tid = blockIdx.x * blockDim.x + t;
    int d = tid / HW;
    int n = tid - d * HW;
    int y = n / NW;
    int x = n - y * NW;
    float fx = (float)x, fy = (float)y;
    float depth = dvals[tid];
    float sum[NC], sq[NC];
#pragma unroll
    for (int c = 0; c < NC; ++c) {
        float r = feats[c * HW + n];
        sum[c] = r; sq[c] = r * r;
    }
#pragma unroll
    for (int v = 0; v < 2; ++v) {
        const float* m = s_mat + v * 12;
        float rx = m[0] * fx + m[1] * fy + m[2];
        float ry = m[3] * fx + m[4] * fy + m[5];
        float rz = m[6] * fx + m[7] * fy + m[8];
        float pxn = rx * depth + m[9];
        float pyn = ry * depth + m[10];
        float z   = rz * depth + m[11];
        z = (fabsf(z) < 1e-6f) ? 1e-6f : z;
        float rzi = __builtin_amdgcn_rcpf(z);
        float px = pxn * rzi, py = pyn * rzi;
        float x0f = floorf(px), y0f = floorf(py);
        float wx = px - x0f, wy = py - y0f;
        int x0 = (int)x0f, y0 = (int)y0f;
        int x1 = x0 + 1, y1 = y0 + 1;
        bool vx0 = (x0 >= 0) && (x0 < NW), vx1 = (x1 >= 0) && (x1 < NW);
        bool vy0 = (y0 >= 0) && (y0 < NH), vy1 = (y1 >= 0) && (y1 < NH);
        int cx0 = min(max(x0, 0), NW - 1), cx1 = min(max(x1, 0), NW - 1);
        int cy0 = min(max(y0, 0), NH - 1), cy1 = min(max(y1, 0), NH - 1);
        int i00 = cy0 * NW + cx0, i01 = cy0 * NW + cx1;
        int i10 = cy1 * NW + cx0, i11 = cy1 * NW + cx1;
        float w00 = (1.f - wx) * (1.f - wy) * ((vx0 && vy0) ? 1.f : 0.f);
        float w01 = wx * (1.f - wy) * ((vx1 && vy0) ? 1.f : 0.f);
        float w10 = (1.f - wx) * wy * ((vx0 && vy1) ? 1.f : 0.f);
        float w11 = wx * wy * ((vx1 && vy1) ? 1.f : 0.f);
        const float* fv = feats + (v + 1) * NC * HW;
#pragma unroll
        for (int c = 0; c < NC; ++c) {
            const float* fc = fv + c * HW;
            float val = fc[i00] * w00 + fc[i01] * w01 + fc[i10] * w10 + fc[i11] * w11;
            sum[c] += val;
            sq[c] += val * val;
        }
    }
    float cst = 0.f;
    const float invV = 1.f / 3.f;
#pragma unroll
    for (int c = 0; c < NC; ++c) {
        float s = sum[c] * invV;
        float var = sq[c] * invV - s * s;
        cst += var * s_w[c];
    }
    cost[tid] = cst;
}

// ---------------------------------------------------------------------------
// Softmax over D + depth regression + confidence (unchanged from R1).
// ---------------------------------------------------------------------------
__global__ __launch_bounds__(256) void softmax_kernel(
    const float* __restrict__ dvals,
    float* __restrict__ out)
{
    int n = blockIdx.x * blockDim.x + threadIdx.x;
    float* prob = out + 2 * HW;

    float c[ND];
    float mx = -INFINITY;
#pragma unroll
    for (int d = 0; d < ND; ++d) {
        c[d] = prob[d * HW + n];
        mx = fmaxf(mx, c[d]);
    }
    float ssum = 0.f;
#pragma unroll
    for (int d = 0; d < ND; ++d) {
        float e = expf(c[d] - mx);
        c[d] = e;
        ssum += e;
    }
    float inv = 1.f / ssum;
    float depth_acc = 0.f, didx_acc = 0.f;
#pragma unroll
    for (int d = 0; d < ND; ++d) {
        float pv = c[d] * inv;
        c[d] = pv;
        prob[d * HW + n] = pv;
        depth_acc += pv * dvals[d * HW + n];
        didx_acc += pv * (float)d;
    }
    int di = (int)didx_acc;
    di = min(max(di, 0), ND - 1);
    float pdi = 0.f, pdi1 = 0.f;
#pragma unroll
    for (int d = 0; d < ND; ++d) {
        pdi = (d == di) ? c[d] : pdi;
        pdi1 = (d == di + 1) ? c[d] : pdi1;
    }
    out[n] = depth_acc;
    out[HW + n] = pdi + pdi1;
}

extern "C" void kernel_launch(void* const* d_in, const int* in_sizes, int n_in,
                              void* d_out, int out_size, void* d_ws, size_t ws_size,
                              hipStream_t stream) {
    const float* feats = (const float*)d_in[0];
    const float* pm    = (const float*)d_in[1];
    const float* dvals = (const float*)d_in[2];
    const float* wreg  = (const float*)d_in[3];
    float* out = (float*)d_out;
    float* mats = (float*)d_ws;

    proj_setup_kernel<<<1, 64, 0, stream>>>(pm, mats);

    if (ws_size >= FT_OFF + FT_BYTES) {
        float* ft = (float*)((char*)d_ws + FT_OFF);
        transpose_kernel<<<2 * HW * 4 / 256, 256, 0, stream>>>(feats, ft);
        cost_kernel2<<<DHW / 256, 256, 0, stream>>>(feats, (const float4*)ft,
                                                    dvals, wreg, mats,
                                                    out + 2 * HW);
    } else {
        cost_kernel<<<DHW / 256, 256, 0, stream>>>(feats, dvals, wreg, mats,
                                                   out + 2 * HW);
    }
    softmax_kernel<<<HW / 256, 256, 0, stream>>>(dvals, out);
}

// Round 3
// 81.629 us; speedup vs baseline: 1.9887x; 1.9887x over previous
//
#include <hip/hip_runtime.h>
#include <math.h>

namespace {
constexpr int NV = 3;    // views
constexpr int NC = 16;   // channels
constexpr int ND = 32;   // depths
constexpr int NH = 256;
constexpr int NW = 320;
constexpr int HW = NH * NW;       // 81920
}

// ---------------------------------------------------------------------------
// Setup: proj_v = P_v @ inv(P_0); store rot(9)+trans(3) per src view.
// ---------------------------------------------------------------------------
__global__ void proj_setup_kernel(const float* __restrict__ pm,
                                  float* __restrict__ mats) {
    if (threadIdx.x != 0 || blockIdx.x != 0) return;
    float P[NV][4][4];
    for (int v = 0; v < NV; ++v) {
        const float* E = pm + v * 2 * 16;
        const float* K = pm + v * 2 * 16 + 16;
        for (int i = 0; i < 4; ++i)
            for (int j = 0; j < 4; ++j)
                P[v][i][j] = E[i * 4 + j];
        for (int i = 0; i < 3; ++i)
            for (int j = 0; j < 4; ++j) {
                float acc = 0.f;
                for (int k = 0; k < 3; ++k) acc += K[i * 4 + k] * E[k * 4 + j];
                P[v][i][j] = acc;
            }
    }
    float A[4][8];
    for (int i = 0; i < 4; ++i)
        for (int j = 0; j < 4; ++j) {
            A[i][j] = P[0][i][j];
            A[i][j + 4] = (i == j) ? 1.f : 0.f;
        }
    for (int col = 0; col < 4; ++col) {
        int piv = col;
        float best = fabsf(A[col][col]);
        for (int r = col + 1; r < 4; ++r) {
            float av = fabsf(A[r][col]);
            if (av > best) { best = av; piv = r; }
        }
        if (piv != col)
            for (int j = 0; j < 8; ++j) {
                float t = A[col][j]; A[col][j] = A[piv][j]; A[piv][j] = t;
            }
        float inv = 1.f / A[col][col];
        for (int j = 0; j < 8; ++j) A[col][j] *= inv;
        for (int r = 0; r < 4; ++r) {
            if (r == col) continue;
            float f = A[r][col];
            if (f != 0.f)
                for (int j = 0; j < 8; ++j) A[r][j] -= f * A[col][j];
        }
    }
    float Inv[4][4];
    for (int i = 0; i < 4; ++i)
        for (int j = 0; j < 4; ++j) Inv[i][j] = A[i][j + 4];

    for (int v = 1; v < NV; ++v) {
        float M[4][4];
        for (int i = 0; i < 4; ++i)
            for (int j = 0; j < 4; ++j) {
                float acc = 0.f;
                for (int k = 0; k < 4; ++k) acc += P[v][i][k] * Inv[k][j];
                M[i][j] = acc;
            }
        float* o = mats + (v - 1) * 12;
        for (int i = 0; i < 3; ++i)
            for (int j = 0; j < 3; ++j) o[i * 3 + j] = M[i][j];
        for (int i = 0; i < 3; ++i) o[9 + i] = M[i][3];
    }
}

// ---------------------------------------------------------------------------
// Cost volume. [C][HW] layout (gathers coalesce across lanes since adjacent
// pixels project to adjacent source pixels). One thread per (pixel, dpair);
// handles depths dp and dp+16 sequentially (shares ref loads + rot·xy).
// Loads use uniform SGPR channel bases + shared unsigned 32-bit byte offsets
// so per-gather address VALU is ~zero.
// block = 320 threads (one image row) -> no integer division anywhere.
// ---------------------------------------------------------------------------
__global__ __launch_bounds__(320, 4) void cost_kernel3(
    const float* __restrict__ feats,   // [V][C][HW]
    const float* __restrict__ dvals,   // [D][HW]
    const float* __restrict__ wreg,    // [C]
    const float* __restrict__ mats,    // [2][12]
    float* __restrict__ cost)          // [D][HW]
{
    const int x = threadIdx.x;
    const int y = blockIdx.x;
    const int dp = blockIdx.y;          // 0..15
    const unsigned n = (unsigned)(y * NW + x);
    const float fx = (float)x, fy = (float)y;

    // ref features, loaded once, reused for both depths
    float rf[NC];
#pragma unroll
    for (int c = 0; c < NC; ++c)
        rf[c] = (feats + (size_t)c * HW)[n];

    // per-view rot * (x,y,1), shared across depths (mats via scalar loads)
    float rxv[2], ryv[2], rzv[2];
#pragma unroll
    for (int v = 0; v < 2; ++v) {
        const float* m = mats + v * 12;
        rxv[v] = m[0] * fx + m[1] * fy + m[2];
        ryv[v] = m[3] * fx + m[4] * fy + m[5];
        rzv[v] = m[6] * fx + m[7] * fy + m[8];
    }

    for (int dd = 0; dd < 2; ++dd) {     // NOT unrolled: keep register pressure low
        const int d = dp + dd * 16;
        const float depth = (dvals + (size_t)d * HW)[n];

        float sum[NC], sq[NC];
#pragma unroll
        for (int c = 0; c < NC; ++c) {
            sum[c] = rf[c];
            sq[c] = rf[c] * rf[c];
        }

#pragma unroll
        for (int v = 0; v < 2; ++v) {
            const float* m = mats + v * 12;
            float pxn = rxv[v] * depth + m[9];
            float pyn = ryv[v] * depth + m[10];
            float z   = rzv[v] * depth + m[11];
            z = (fabsf(z) < 1e-6f) ? 1e-6f : z;
            float r0 = __builtin_amdgcn_rcpf(z);
            r0 = r0 * (2.0f - z * r0);          // Newton: ~exact-div accuracy
            float px = pxn * r0, py = pyn * r0;
            float x0f = floorf(px), y0f = floorf(py);
            float wx = px - x0f, wy = py - y0f;
            int x0 = (int)x0f, y0 = (int)y0f;
            int x1 = x0 + 1, y1 = y0 + 1;
            bool vx0 = (x0 >= 0) && (x0 < NW), vx1 = (x1 >= 0) && (x1 < NW);
            bool vy0 = (y0 >= 0) && (y0 < NH), vy1 = (y1 >= 0) && (y1 < NH);
            int cx0 = min(max(x0, 0), NW - 1), cx1 = min(max(x1, 0), NW - 1);
            int cy0 = min(max(y0, 0), NH - 1), cy1 = min(max(y1, 0), NH - 1);
            // shared 32-bit byte offsets for all 16 channels
            unsigned o00 = (unsigned)(cy0 * NW + cx0) * 4u;
            unsigned o01 = (unsigned)(cy0 * NW + cx1) * 4u;
            unsigned o10 = (unsigned)(cy1 * NW + cx0) * 4u;
            unsigned o11 = (unsigned)(cy1 * NW + cx1) * 4u;
            float w00 = (1.f - wx) * (1.f - wy) * ((vx0 && vy0) ? 1.f : 0.f);
            float w01 = wx * (1.f - wy) * ((vx1 && vy0) ? 1.f : 0.f);
            float w10 = (1.f - wx) * wy * ((vx0 && vy1) ? 1.f : 0.f);
            float w11 = wx * wy * ((vx1 && vy1) ? 1.f : 0.f);

            const char* fvb = (const char*)(feats + (size_t)(v + 1) * NC * HW);
#pragma unroll
            for (int c = 0; c < NC; ++c) {
                const char* fcb = fvb + (size_t)c * HW * 4;   // uniform SGPR base
                float g00 = *(const float*)(fcb + o00);
                float g01 = *(const float*)(fcb + o01);
                float g10 = *(const float*)(fcb + o10);
                float g11 = *(const float*)(fcb + o11);
                float val = g00 * w00 + g01 * w01 + g10 * w10 + g11 * w11;
                sum[c] += val;
                sq[c] = fmaf(val, val, sq[c]);
            }
        }

        float cst = 0.f;
        const float invV = 1.f / 3.f;
#pragma unroll
        for (int c = 0; c < NC; ++c) {
            float s = sum[c] * invV;
            float var = fmaf(sq[c], invV, -(s * s));
            cst = fmaf(var, wreg[c], cst);
        }
        (cost + (size_t)d * HW)[n] = cst;
    }
}

// ---------------------------------------------------------------------------
// Softmax over D + depth regression + confidence (reads cost from prob
// region of d_out, overwrites with prob).
// ---------------------------------------------------------------------------
__global__ __launch_bounds__(256) void softmax_kernel(
    const float* __restrict__ dvals,
    float* __restrict__ out)
{
    int n = blockIdx.x * blockDim.x + threadIdx.x;
    float* prob = out + 2 * HW;

    float c[ND];
    float mx = -INFINITY;
#pragma unroll
    for (int d = 0; d < ND; ++d) {
        c[d] = prob[d * HW + n];
        mx = fmaxf(mx, c[d]);
    }
    float ssum = 0.f;
#pragma unroll
    for (int d = 0; d < ND; ++d) {
        float e = expf(c[d] - mx);
        c[d] = e;
        ssum += e;
    }
    float inv = 1.f / ssum;
    float depth_acc = 0.f, didx_acc = 0.f;
#pragma unroll
    for (int d = 0; d < ND; ++d) {
        float pv = c[d] * inv;
        c[d] = pv;
        prob[d * HW + n] = pv;
        depth_acc += pv * dvals[d * HW + n];
        didx_acc += pv * (float)d;
    }
    int di = (int)didx_acc;            // trunc toward zero, matches astype(int32)
    di = min(max(di, 0), ND - 1);
    float pdi = 0.f, pdi1 = 0.f;
#pragma unroll
    for (int d = 0; d < ND; ++d) {
        pdi = (d == di) ? c[d] : pdi;
        pdi1 = (d == di + 1) ? c[d] : pdi1;
    }
    out[n] = depth_acc;
    out[HW + n] = pdi + pdi1;
}

extern "C" void kernel_launch(void* const* d_in, const int* in_sizes, int n_in,
                              void* d_out, int out_size, void* d_ws, size_t ws_size,
                              hipStream_t stream) {
    const float* feats = (const float*)d_in[0];
    const float* pm    = (const float*)d_in[1];
    const float* dvals = (const float*)d_in[2];
    const float* wreg  = (const float*)d_in[3];
    float* out = (float*)d_out;
    float* mats = (float*)d_ws;                  // 24 floats

    proj_setup_kernel<<<1, 64, 0, stream>>>(pm, mats);
    cost_kernel3<<<dim3(NH, 16), 320, 0, stream>>>(feats, dvals, wreg, mats,
                                                   out + 2 * HW);
    softmax_kernel<<<HW / 256, 256, 0, stream>>>(dvals, out);
}

// Round 4
// 65.938 us; speedup vs baseline: 2.4620x; 1.2380x over previous
//
#include <hip/hip_runtime.h>
#include <math.h>

namespace {
constexpr int NV = 3;    // views
constexpr int NC = 16;   // channels
constexpr int ND = 32;   // depths
constexpr int NH = 256;
constexpr int NW = 320;
constexpr int HW = NH * NW;       // 81920
}

// ---------------------------------------------------------------------------
// Setup: proj_v = P_v @ inv(P_0); store rot(9)+trans(3) per src view.
// ---------------------------------------------------------------------------
__global__ void proj_setup_kernel(const float* __restrict__ pm,
                                  float* __restrict__ mats) {
    if (threadIdx.x != 0 || blockIdx.x != 0) return;
    float P[NV][4][4];
    for (int v = 0; v < NV; ++v) {
        const float* E = pm + v * 2 * 16;
        const float* K = pm + v * 2 * 16 + 16;
        for (int i = 0; i < 4; ++i)
            for (int j = 0; j < 4; ++j)
                P[v][i][j] = E[i * 4 + j];
        for (int i = 0; i < 3; ++i)
            for (int j = 0; j < 4; ++j) {
                float acc = 0.f;
                for (int k = 0; k < 3; ++k) acc += K[i * 4 + k] * E[k * 4 + j];
                P[v][i][j] = acc;
            }
    }
    float A[4][8];
    for (int i = 0; i < 4; ++i)
        for (int j = 0; j < 4; ++j) {
            A[i][j] = P[0][i][j];
            A[i][j + 4] = (i == j) ? 1.f : 0.f;
        }
    for (int col = 0; col < 4; ++col) {
        int piv = col;
        float best = fabsf(A[col][col]);
        for (int r = col + 1; r < 4; ++r) {
            float av = fabsf(A[r][col]);
            if (av > best) { best = av; piv = r; }
        }
        if (piv != col)
            for (int j = 0; j < 8; ++j) {
                float t = A[col][j]; A[col][j] = A[piv][j]; A[piv][j] = t;
            }
        float inv = 1.f / A[col][col];
        for (int j = 0; j < 8; ++j) A[col][j] *= inv;
        for (int r = 0; r < 4; ++r) {
            if (r == col) continue;
            float f = A[r][col];
            if (f != 0.f)
                for (int j = 0; j < 8; ++j) A[r][j] -= f * A[col][j];
        }
    }
    float Inv[4][4];
    for (int i = 0; i < 4; ++i)
        for (int j = 0; j < 4; ++j) Inv[i][j] = A[i][j + 4];

    for (int v = 1; v < NV; ++v) {
        float M[4][4];
        for (int i = 0; i < 4; ++i)
            for (int j = 0; j < 4; ++j) {
                float acc = 0.f;
                for (int k = 0; k < 4; ++k) acc += P[v][i][k] * Inv[k][j];
                M[i][j] = acc;
            }
        float* o = mats + (v - 1) * 12;
        for (int i = 0; i < 3; ++i)
            for (int j = 0; j < 3; ++j) o[i * 3 + j] = M[i][j];
        for (int i = 0; i < 3; ++i) o[9 + i] = M[i][3];
    }
}

// ---------------------------------------------------------------------------
// Cost volume. One thread per (d, n): 2.62M threads, 4-wave blocks (best
// occupancy packing — R3's 5-wave/2-depth variant halved resident waves and
// regressed). [C][HW] layout keeps gathers lane-coherent (~2-3 cache lines
// per wave-load; the [HW][C] float4 variant touched 64 lines/load and was
// 2.5x slower). Uniform SGPR channel bases + shared unsigned byte offsets
// -> ~zero address VALU per gather.
// ---------------------------------------------------------------------------
__global__ __launch_bounds__(256) void cost_kernel4(
    const float* __restrict__ feats,   // [V][C][HW]
    const float* __restrict__ dvals,   // [D][HW]
    const float* __restrict__ wreg,    // [C]
    const float* __restrict__ mats,    // [2][12]
    float* __restrict__ cost)          // [D][HW]
{
    const int d = blockIdx.y;
    const unsigned n = blockIdx.x * 256u + threadIdx.x;
    const int y = (int)(n / NW);
    const int x = (int)(n - (unsigned)y * NW);
    const float fx = (float)x, fy = (float)y;
    const unsigned voff = n * 4u;

    const float depth = *(const float*)((const char*)dvals +
                                        (size_t)d * HW * 4 + voff);

    float sum[NC], sq[NC];
#pragma unroll
    for (int c = 0; c < NC; ++c) {
        float r = *(const float*)((const char*)feats + (size_t)c * HW * 4 + voff);
        sum[c] = r;
        sq[c] = r * r;
    }

#pragma unroll
    for (int v = 0; v < 2; ++v) {
        const float* m = mats + v * 12;   // uniform -> scalar loads
        float rx = fmaf(m[0], fx, fmaf(m[1], fy, m[2]));
        float ry = fmaf(m[3], fx, fmaf(m[4], fy, m[5]));
        float rz = fmaf(m[6], fx, fmaf(m[7], fy, m[8]));
        float pxn = fmaf(rx, depth, m[9]);
        float pyn = fmaf(ry, depth, m[10]);
        float z   = fmaf(rz, depth, m[11]);
        z = (fabsf(z) < 1e-6f) ? 1e-6f : z;
        float r0 = __builtin_amdgcn_rcpf(z);
        r0 = r0 * (2.0f - z * r0);          // Newton refine
        float px = pxn * r0, py = pyn * r0;
        float x0f = floorf(px), y0f = floorf(py);
        float wx = px - x0f, wy = py - y0f;
        int x0 = (int)x0f, y0 = (int)y0f;
        int x1 = x0 + 1, y1 = y0 + 1;
        bool vx0 = (x0 >= 0) && (x0 < NW), vx1 = (x1 >= 0) && (x1 < NW);
        bool vy0 = (y0 >= 0) && (y0 < NH), vy1 = (y1 >= 0) && (y1 < NH);
        int cx0 = min(max(x0, 0), NW - 1), cx1 = min(max(x1, 0), NW - 1);
        int cy0 = min(max(y0, 0), NH - 1), cy1 = min(max(y1, 0), NH - 1);
        unsigned o00 = (unsigned)(cy0 * NW + cx0) * 4u;
        unsigned o01 = (unsigned)(cy0 * NW + cx1) * 4u;
        unsigned o10 = (unsigned)(cy1 * NW + cx0) * 4u;
        unsigned o11 = (unsigned)(cy1 * NW + cx1) * 4u;
        float w00 = (1.f - wx) * (1.f - wy) * ((vx0 && vy0) ? 1.f : 0.f);
        float w01 = wx * (1.f - wy) * ((vx1 && vy0) ? 1.f : 0.f);
        float w10 = (1.f - wx) * wy * ((vx0 && vy1) ? 1.f : 0.f);
        float w11 = wx * wy * ((vx1 && vy1) ? 1.f : 0.f);

        const char* fvb = (const char*)(feats + (size_t)(v + 1) * NC * HW);
#pragma unroll
        for (int c = 0; c < NC; ++c) {
            const char* fcb = fvb + (size_t)c * HW * 4;   // uniform SGPR base
            float g00 = *(const float*)(fcb + o00);
            float g01 = *(const float*)(fcb + o01);
            float g10 = *(const float*)(fcb + o10);
            float g11 = *(const float*)(fcb + o11);
            float val = fmaf(g00, w00, fmaf(g01, w01, fmaf(g10, w10, g11 * w11)));
            sum[c] += val;
            sq[c] = fmaf(val, val, sq[c]);
        }
    }

    float cst = 0.f;
    const float invV = 1.f / 3.f;
#pragma unroll
    for (int c = 0; c < NC; ++c) {
        float s = sum[c] * invV;
        float var = fmaf(sq[c], invV, -(s * s));
        cst = fmaf(var, wreg[c], cst);
    }
    *(float*)((char*)cost + (size_t)d * HW * 4 + voff) = cst;
}

// ---------------------------------------------------------------------------
// Softmax over D + depth regression + confidence (reads cost from prob
// region of d_out, overwrites with prob).
// ---------------------------------------------------------------------------
__global__ __launch_bounds__(256) void softmax_kernel(
    const float* __restrict__ dvals,
    float* __restrict__ out)
{
    int n = blockIdx.x * blockDim.x + threadIdx.x;
    float* prob = out + 2 * HW;

    float c[ND];
    float mx = -INFINITY;
#pragma unroll
    for (int d = 0; d < ND; ++d) {
        c[d] = prob[d * HW + n];
        mx = fmaxf(mx, c[d]);
    }
    float ssum = 0.f;
#pragma unroll
    for (int d = 0; d < ND; ++d) {
        float e = expf(c[d] - mx);
        c[d] = e;
        ssum += e;
    }
    float inv = 1.f / ssum;
    float depth_acc = 0.f, didx_acc = 0.f;
#pragma unroll
    for (int d = 0; d < ND; ++d) {
        float pv = c[d] * inv;
        c[d] = pv;
        prob[d * HW + n] = pv;
        depth_acc += pv * dvals[d * HW + n];
        didx_acc += pv * (float)d;
    }
    int di = (int)didx_acc;            // trunc toward zero, matches astype(int32)
    di = min(max(di, 0), ND - 1);
    float pdi = 0.f, pdi1 = 0.f;
#pragma unroll
    for (int d = 0; d < ND; ++d) {
        pdi = (d == di) ? c[d] : pdi;
        pdi1 = (d == di + 1) ? c[d] : pdi1;
    }
    out[n] = depth_acc;
    out[HW + n] = pdi + pdi1;
}

extern "C" void kernel_launch(void* const* d_in, const int* in_sizes, int n_in,
                              void* d_out, int out_size, void* d_ws, size_t ws_size,
                              hipStream_t stream) {
    const float* feats = (const float*)d_in[0];
    const float* pm    = (const float*)d_in[1];
    const float* dvals = (const float*)d_in[2];
    const float* wreg  = (const float*)d_in[3];
    float* out = (float*)d_out;
    float* mats = (float*)d_ws;                  // 24 floats

    proj_setup_kernel<<<1, 64, 0, stream>>>(pm, mats);
    cost_kernel4<<<dim3(HW / 256, ND), 256, 0, stream>>>(feats, dvals, wreg,
                                                         mats, out + 2 * HW);
    softmax_kernel<<<HW / 256, 256, 0, stream>>>(dvals, out);
}

// Round 5
// 65.192 us; speedup vs baseline: 2.4901x; 1.0114x over previous
//
#include <hip/hip_runtime.h>
#include <math.h>

namespace {
constexpr int NV = 3;    // views
constexpr int NC = 16;   // channels
constexpr int ND = 32;   // depths
constexpr int NH = 256;
constexpr int NW = 320;
constexpr int HW = NH * NW;       // 81920
}

// ---------------------------------------------------------------------------
// Setup: proj_v = P_v @ inv(P_0); store rot(9)+trans(3) per src view.
// ---------------------------------------------------------------------------
__global__ void proj_setup_kernel(const float* __restrict__ pm,
                                  float* __restrict__ mats) {
    if (threadIdx.x != 0 || blockIdx.x != 0) return;
    float P[NV][4][4];
    for (int v = 0; v < NV; ++v) {
        const float* E = pm + v * 2 * 16;
        const float* K = pm + v * 2 * 16 + 16;
        for (int i = 0; i < 4; ++i)
            for (int j = 0; j < 4; ++j)
                P[v][i][j] = E[i * 4 + j];
        for (int i = 0; i < 3; ++i)
            for (int j = 0; j < 4; ++j) {
                float acc = 0.f;
                for (int k = 0; k < 3; ++k) acc += K[i * 4 + k] * E[k * 4 + j];
                P[v][i][j] = acc;
            }
    }
    float A[4][8];
    for (int i = 0; i < 4; ++i)
        for (int j = 0; j < 4; ++j) {
            A[i][j] = P[0][i][j];
            A[i][j + 4] = (i == j) ? 1.f : 0.f;
        }
    for (int col = 0; col < 4; ++col) {
        int piv = col;
        float best = fabsf(A[col][col]);
        for (int r = col + 1; r < 4; ++r) {
            float av = fabsf(A[r][col]);
            if (av > best) { best = av; piv = r; }
        }
        if (piv != col)
            for (int j = 0; j < 8; ++j) {
                float t = A[col][j]; A[col][j] = A[piv][j]; A[piv][j] = t;
            }
        float inv = 1.f / A[col][col];
        for (int j = 0; j < 8; ++j) A[col][j] *= inv;
        for (int r = 0; r < 4; ++r) {
            if (r == col) continue;
            float f = A[r][col];
            if (f != 0.f)
                for (int j = 0; j < 8; ++j) A[r][j] -= f * A[col][j];
        }
    }
    float Inv[4][4];
    for (int i = 0; i < 4; ++i)
        for (int j = 0; j < 4; ++j) Inv[i][j] = A[i][j + 4];

    for (int v = 1; v < NV; ++v) {
        float M[4][4];
        for (int i = 0; i < 4; ++i)
            for (int j = 0; j < 4; ++j) {
                float acc = 0.f;
                for (int k = 0; k < 4; ++k) acc += P[v][i][k] * Inv[k][j];
                M[i][j] = acc;
            }
        float* o = mats + (v - 1) * 12;
        for (int i = 0; i < 3; ++i)
            for (int j = 0; j < 3; ++j) o[i * 3 + j] = M[i][j];
        for (int i = 0; i < 3; ++i) o[9 + i] = M[i][3];
    }
}

// ---------------------------------------------------------------------------
// Cost volume. One thread per (d, n), 256-thread blocks. [C][HW] layout keeps
// gathers lane-coherent (~2-3 cache lines per wave-load). Uniform SGPR
// channel bases + shared unsigned byte offsets -> ~zero address VALU per
// gather. NEW in R5: per-view gathers batched into registers BEFORE the
// arithmetic loop (64-deep MLP instead of ~12), with __launch_bounds__(256,4)
// granting ~128 VGPR. R4's 40-VGPR version was latency-stalled on gathers
// (VALUBusy 46%, occ 51%, but dur 2x the overlap model).
// ---------------------------------------------------------------------------
__global__ __launch_bounds__(256, 4) void cost_kernel5(
    const float* __restrict__ feats,   // [V][C][HW]
    const float* __restrict__ dvals,   // [D][HW]
    const float* __restrict__ wreg,    // [C]
    const float* __restrict__ mats,    // [2][12]
    float* __restrict__ cost)          // [D][HW]
{
    const int d = blockIdx.y;
    const unsigned n = blockIdx.x * 256u + threadIdx.x;
    const int y = (int)(n / NW);
    const int x = (int)(n - (unsigned)y * NW);
    const float fx = (float)x, fy = (float)y;
    const unsigned voff = n * 4u;

    const float depth = *(const float*)((const char*)dvals +
                                        (size_t)d * HW * 4 + voff);

    float sum[NC], sq[NC];
#pragma unroll
    for (int c = 0; c < NC; ++c) {
        float r = *(const float*)((const char*)feats + (size_t)c * HW * 4 + voff);
        sum[c] = r;
        sq[c] = r * r;
    }

#pragma unroll
    for (int v = 0; v < 2; ++v) {
        const float* m = mats + v * 12;   // uniform -> scalar loads
        float rx = fmaf(m[0], fx, fmaf(m[1], fy, m[2]));
        float ry = fmaf(m[3], fx, fmaf(m[4], fy, m[5]));
        float rz = fmaf(m[6], fx, fmaf(m[7], fy, m[8]));
        float pxn = fmaf(rx, depth, m[9]);
        float pyn = fmaf(ry, depth, m[10]);
        float z   = fmaf(rz, depth, m[11]);
        z = (fabsf(z) < 1e-6f) ? 1e-6f : z;
        float r0 = __builtin_amdgcn_rcpf(z);
        r0 = r0 * (2.0f - z * r0);          // Newton refine
        float px = pxn * r0, py = pyn * r0;
        float x0f = floorf(px), y0f = floorf(py);
        float wx = px - x0f, wy = py - y0f;
        int x0 = (int)x0f, y0 = (int)y0f;
        int x1 = x0 + 1, y1 = y0 + 1;
        bool vx0 = (x0 >= 0) && (x0 < NW), vx1 = (x1 >= 0) && (x1 < NW);
        bool vy0 = (y0 >= 0) && (y0 < NH), vy1 = (y1 >= 0) && (y1 < NH);
        int cx0 = min(max(x0, 0), NW - 1), cx1 = min(max(x1, 0), NW - 1);
        int cy0 = min(max(y0, 0), NH - 1), cy1 = min(max(y1, 0), NH - 1);
        unsigned o00 = (unsigned)(cy0 * NW + cx0) * 4u;
        unsigned o01 = (unsigned)(cy0 * NW + cx1) * 4u;
        unsigned o10 = (unsigned)(cy1 * NW + cx0) * 4u;
        unsigned o11 = (unsigned)(cy1 * NW + cx1) * 4u;
        float w00 = (1.f - wx) * (1.f - wy) * ((vx0 && vy0) ? 1.f : 0.f);
        float w01 = wx * (1.f - wy) * ((vx1 && vy0) ? 1.f : 0.f);
        float w10 = (1.f - wx) * wy * ((vx0 && vy1) ? 1.f : 0.f);
        float w11 = wx * wy * ((vx1 && vy1) ? 1.f : 0.f);

        const char* fvb = (const char*)(feats + (size_t)(v + 1) * NC * HW);

        // -------- batched gather phase: 64 loads issued before any use ----
        float g00[NC], g01[NC], g10[NC], g11[NC];
#pragma unroll
        for (int c = 0; c < NC; ++c) {
            const char* fcb = fvb + (size_t)c * HW * 4;   // uniform SGPR base
            g00[c] = *(const float*)(fcb + o00);
            g01[c] = *(const float*)(fcb + o01);
            g10[c] = *(const float*)(fcb + o10);
            g11[c] = *(const float*)(fcb + o11);
        }
        // -------- consume phase ------------------------------------------
#pragma unroll
        for (int c = 0; c < NC; ++c) {
            float val = fmaf(g00[c], w00,
                        fmaf(g01[c], w01,
                        fmaf(g10[c], w10, g11[c] * w11)));
            sum[c] += val;
            sq[c] = fmaf(val, val, sq[c]);
        }
    }

    float cst = 0.f;
    const float invV = 1.f / 3.f;
#pragma unroll
    for (int c = 0; c < NC; ++c) {
        float s = sum[c] * invV;
        float var = fmaf(sq[c], invV, -(s * s));
        cst = fmaf(var, wreg[c], cst);
    }
    *(float*)((char*)cost + (size_t)d * HW * 4 + voff) = cst;
}

// ---------------------------------------------------------------------------
// Softmax over D + depth regression + confidence (reads cost from prob
// region of d_out, overwrites with prob).
// ---------------------------------------------------------------------------
__global__ __launch_bounds__(256) void softmax_kernel(
    const float* __restrict__ dvals,
    float* __restrict__ out)
{
    int n = blockIdx.x * blockDim.x + threadIdx.x;
    float* prob = out + 2 * HW;

    float c[ND];
    float mx = -INFINITY;
#pragma unroll
    for (int d = 0; d < ND; ++d) {
        c[d] = prob[d * HW + n];
        mx = fmaxf(mx, c[d]);
    }
    float ssum = 0.f;
#pragma unroll
    for (int d = 0; d < ND; ++d) {
        float e = expf(c[d] - mx);
        c[d] = e;
        ssum += e;
    }
    float inv = 1.f / ssum;
    float depth_acc = 0.f, didx_acc = 0.f;
#pragma unroll
    for (int d = 0; d < ND; ++d) {
        float pv = c[d] * inv;
        c[d] = pv;
        prob[d * HW + n] = pv;
        depth_acc += pv * dvals[d * HW + n];
        didx_acc += pv * (float)d;
    }
    int di = (int)didx_acc;            // trunc toward zero, matches astype(int32)
    di = min(max(di, 0), ND - 1);
    float pdi = 0.f, pdi1 = 0.f;
#pragma unroll
    for (int d = 0; d < ND; ++d) {
        pdi = (d == di) ? c[d] : pdi;
        pdi1 = (d == di + 1) ? c[d] : pdi1;
    }
    out[n] = depth_acc;
    out[HW + n] = pdi + pdi1;
}

extern "C" void kernel_launch(void* const* d_in, const int* in_sizes, int n_in,
                              void* d_out, int out_size, void* d_ws, size_t ws_size,
                              hipStream_t stream) {
    const float* feats = (const float*)d_in[0];
    const float* pm    = (const float*)d_in[1];
    const float* dvals = (const float*)d_in[2];
    const float* wreg  = (const float*)d_in[3];
    float* out = (float*)d_out;
    float* mats = (float*)d_ws;                  // 24 floats

    proj_setup_kernel<<<1, 64, 0, stream>>>(pm, mats);
    cost_kernel5<<<dim3(HW / 256, ND), 256, 0, stream>>>(feats, dvals, wreg,
                                                         mats, out + 2 * HW);
    softmax_kernel<<<HW / 256, 256, 0, stream>>>(dvals, out);
}